// Round 6
// baseline (53812.720 us; speedup 1.0000x reference)
//
#include <hip/hip_runtime.h>

#define NINP 34
#define NCC  128
#define NHH  512
#define BBB  64
#define SSS  2048
#define TTT  400
#define GEPS 1e-10f

#define GDIM 512
#define NTHR 256
#define NCHK 8        // attention S-chunks
#define SCHK 256      // S per chunk

#define JAX_PARTITIONABLE 1

// ws float offsets (after 8192-byte sync header)
#define OFF_H   0          // h double buffer: 2*3*B*NH = 196608
#define OFF_C   196608     // c: 3*B*NH = 98304
#define OFF_CTX 294912     // B*NC = 8192
#define OFF_ML  303104     // B*8 = 512 (m, L per batch)
#define OFF_P   303616     // B*NCHK*132 = 67584

// sync word layout (2048 uints), all monotonic counters
#define SY_ROOT 0
#define SY_GEN  16
#define SY_LEAFC(l) (256 + 8 * (l))
#define SY_LEAFG(l) (512 + 8 * (l))
#define SY_CTXH(h)  (768 + 64 * (h))   // per-batch-half ctx-ready, 32 posts/step
#define SY_BF(b)    (1024 + 8 * (b))
#define SY_MF(b)    (1536 + 8 * (b))

struct Params {
  const float* keys; const float* values;
  const int* lens;  const int* toks;
  const float* emb; const float* wq; const float* bq;
  const float* wc;  const float* bc; const float* bout;
  const float* wih[3]; const float* whh[3];
  const float* bih[3]; const float* bhh[3];
  const float* h0[3];  const float* c0[3];
  float* out_logits; float* out_att; float* out_gen;
  float* wsf; unsigned* sync;
};

__device__ __forceinline__ float4 ld4(const float* p) { return *(const float4*)p; }
__device__ __forceinline__ float sigf(float x) { return 1.0f / (1.0f + expf(-x)); }

// ---- relaxed agent-scope ops (sc1, to the IF coherence point). No
// acquire/release (buffer_inv / wbl2 = pathology). Ordering is manual:
// s_waitcnt vmcnt(0) on producer side + compiler barriers.
__device__ __forceinline__ unsigned aload(const unsigned* p) {
  return __hip_atomic_load(p, __ATOMIC_RELAXED, __HIP_MEMORY_SCOPE_AGENT);
}
__device__ __forceinline__ unsigned aadd(unsigned* p, unsigned v) {
  return __hip_atomic_fetch_add(p, v, __ATOMIC_RELAXED, __HIP_MEMORY_SCOPE_AGENT);
}
__device__ __forceinline__ void astore(unsigned* p, unsigned v) {
  __hip_atomic_store(p, v, __ATOMIC_RELAXED, __HIP_MEMORY_SCOPE_AGENT);
}
__device__ __forceinline__ float ldc(const float* p) {
  unsigned u = __hip_atomic_load((const unsigned*)p, __ATOMIC_RELAXED, __HIP_MEMORY_SCOPE_AGENT);
  return __uint_as_float(u);
}
__device__ __forceinline__ void stc(float* p, float v) {
  __hip_atomic_store((unsigned*)p, __float_as_uint(v), __ATOMIC_RELAXED, __HIP_MEMORY_SCOPE_AGENT);
}
__device__ __forceinline__ float4 ld4c(const float* p) {
  unsigned long long a = __hip_atomic_load((const unsigned long long*)p,
                                           __ATOMIC_RELAXED, __HIP_MEMORY_SCOPE_AGENT);
  unsigned long long b = __hip_atomic_load(((const unsigned long long*)p) + 1,
                                           __ATOMIC_RELAXED, __HIP_MEMORY_SCOPE_AGENT);
  float4 r;
  r.x = __uint_as_float((unsigned)a); r.y = __uint_as_float((unsigned)(a >> 32));
  r.z = __uint_as_float((unsigned)b); r.w = __uint_as_float((unsigned)(b >> 32));
  return r;
}
__device__ __forceinline__ void wait_vm0() {
  asm volatile("s_waitcnt vmcnt(0)" ::: "memory");
}
__device__ __forceinline__ void cbar() { asm volatile("" ::: "memory"); }

// Tree grid barrier: 32 leaves x 16 blocks. Release fans out via per-leaf
// generation words so no line has >32 pollers.
__device__ void gbar(unsigned* sync, unsigned& epoch, int bid) {
  wait_vm0();
  __syncthreads();
  if (threadIdx.x == 0) {
    epoch++;
    const int leaf = bid >> 4;
    const bool leader = (bid & 15) == 0;
    if (aadd(&sync[SY_LEAFC(leaf)], 1u) == 16u * epoch - 1u) {
      if (aadd(&sync[SY_ROOT], 1u) == 32u * epoch - 1u)
        astore(&sync[SY_GEN], epoch);
    }
    if (leader) {
      while (aload(&sync[SY_GEN]) < epoch) __builtin_amdgcn_s_sleep(1);
      astore(&sync[SY_LEAFG(leaf)], epoch);
    } else {
      while (aload(&sync[SY_LEAFG(leaf)]) < epoch) __builtin_amdgcn_s_sleep(1);
    }
  }
  __syncthreads();
  cbar();
}

__device__ __forceinline__ void waitflag(unsigned* p, unsigned target) {
  if (threadIdx.x == 0) {
    while (aload(p) < target) __builtin_amdgcn_s_sleep(2);
  }
  __syncthreads();
  cbar();
}
__device__ __forceinline__ void postflag(unsigned* p) {
  wait_vm0();
  __syncthreads();
  if (threadIdx.x == 0) aadd(p, 1u);
}
__device__ __forceinline__ void postflag2(unsigned* p0, unsigned* p1) {
  wait_vm0();
  __syncthreads();
  if (threadIdx.x == 0) { aadd(p0, 1u); aadd(p1, 1u); }
}

// ---------------- Threefry2x32-20, jax.random.key(1) ----------------
__device__ __forceinline__ void tfr(unsigned& x0, unsigned& x1, int r) {
  x0 += x1; x1 = (x1 << r) | (x1 >> (32 - r)); x1 ^= x0;
}
__device__ unsigned threefry_bits(unsigned idx) {
  const unsigned k0 = 0u, k1 = 1u;
  const unsigned k2 = 0x1BD11BDAu ^ k0 ^ k1;
#if JAX_PARTITIONABLE
  unsigned x0 = 0u, x1 = idx;
#else
  const unsigned half = (TTT * BBB * NINP) / 2;
  const bool lo = idx < half;
  unsigned x0 = lo ? idx : idx - half;
  unsigned x1 = lo ? idx + half : idx;
#endif
  x0 += k0; x1 += k1;
  tfr(x0,x1,13); tfr(x0,x1,15); tfr(x0,x1,26); tfr(x0,x1,6);
  x0 += k1; x1 += k2 + 1u;
  tfr(x0,x1,17); tfr(x0,x1,29); tfr(x0,x1,16); tfr(x0,x1,24);
  x0 += k2; x1 += k0 + 2u;
  tfr(x0,x1,13); tfr(x0,x1,15); tfr(x0,x1,26); tfr(x0,x1,6);
  x0 += k0; x1 += k1 + 3u;
  tfr(x0,x1,17); tfr(x0,x1,29); tfr(x0,x1,16); tfr(x0,x1,24);
  x0 += k1; x1 += k2 + 4u;
  tfr(x0,x1,13); tfr(x0,x1,15); tfr(x0,x1,26); tfr(x0,x1,6);
  x0 += k2; x1 += k0 + 5u;
#if JAX_PARTITIONABLE
  return x0 ^ x1;
#else
  return lo ? x0 : x1;
#endif
}
__device__ __forceinline__ float gumbel(unsigned idx) {
  unsigned bits = threefry_bits(idx);
  float u = __uint_as_float((bits >> 9) | 0x3f800000u) - 1.0f;
  u = fmaxf(u, 0.0f);
  return -logf(GEPS - logf(u + GEPS));
}

// ---------------- LSTM layer phase ----------------
// Block = (unit-pair up, batch-half bh): 8 gate-rows x 32 batches.
// Tri-buffered staging with TWO prefetch register sets: chunk k's loads are
// issued at iteration k-2 and committed at the end of iteration k-1, so they
// get ~2 FMA periods of flight time to cover the L3 round trip.
template<int L>
__device__ void lstm_layer(const Params& p, int t, const float* hin, float* hout,
                           float* sh, int up, int bh, int tid, unsigned* sync) {
  const float* hin_l = hin + L * BBB * NHH + (size_t)bh * 32 * NHH;
  float* houtl = hout + L * BBB * NHH;
  float* cl = p.wsf + OFF_C + L * BBB * NHH;
  const float* xlow = (L == 0) ? (const float*)0
                               : (hout + (L - 1) * BBB * NHH + (size_t)bh * 32 * NHH);

  constexpr int insz = (L == 0) ? (2 * NCC) : NHH;
  constexpr int nx = insz >> 7;
  constexpr int nch = nx + 4;

  const int rhat = tid >> 5;          // 0..7 : (g = rhat>>1, jh = rhat&1)
  const int bloc = tid & 31;          // 0..31
  const int g = rhat >> 1, jh = rhat & 1;
  const int j = 2 * up + jh;
  const int row = g * NHH + j;
  const float* wr  = p.wih[L] + (size_t)row * insz;
  const float* wr2 = p.whh[L] + (size_t)row * NHH;

  float* const xb0 = sh;              // 3 x (32 x 132)
  float* const xb1 = sh + 4224;
  float* const xb2 = sh + 8448;
  const int kk  = (tid & 31) << 2;    // 0..124
  const int rb0 = tid >> 5;           // 0..7

  float4 pfA[4], pfB[4];
  auto issue = [&](float4 (&pf)[4], int cc) {
#pragma unroll
    for (int it = 0; it < 4; ++it) {
      const int rb = rb0 + (it << 3);        // local batch 0..31
      const int gb = bh * 32 + rb;           // global batch
      const bool isx = cc < nx;
      const int off = (isx ? cc : cc - nx) << 7;
      if (L == 0) {
        if (isx) pf[it] = (cc == 0)
            ? ld4(p.emb + (size_t)p.toks[gb * TTT + t] * NCC + kk)   // read-only
            : ld4c(p.wsf + OFF_CTX + gb * NCC + kk);                 // kernel-written
        else pf[it] = ld4c(hin_l + (size_t)rb * NHH + off + kk);
      } else {
        pf[it] = isx ? ld4c(xlow + (size_t)rb * NHH + off + kk)
                     : ld4c(hin_l + (size_t)rb * NHH + off + kk);
      }
    }
  };
  auto commit = [&](float4 (&pf)[4], float* buf) {
#pragma unroll
    for (int it = 0; it < 4; ++it)
      *(float4*)&buf[(rb0 + (it << 3)) * 132 + kk] = pf[it];
  };

  float acc = p.bih[L][row] + p.bhh[L][row];
  float s0 = 0.f, s1 = 0.f, s2 = 0.f, s3 = 0.f;

  issue(pfA, 0);                       // chunk0 (L0: emb — needs no ctx)
  if (L == 0) {
    // ctx for this batch-half: 32 combine posts from the preceding attend
    waitflag(&sync[SY_CTXH(bh)], 32u * (unsigned)(t + 1));
  }
  commit(pfA, xb0);
  issue(pfB, 1);
  __syncthreads();
#pragma unroll
  for (int cc = 0; cc < nch; ++cc) {
    if (cc + 2 < nch) issue((cc & 1) ? pfB : pfA, cc + 2);   // chunk cc+2 parity == cc parity
    const bool isx = cc < nx;
    const int off = (isx ? cc : cc - nx) << 7;
    const float* wp = (isx ? wr : wr2) + off;
    float* const bufc = (cc % 3 == 0) ? xb0 : (cc % 3 == 1) ? xb1 : xb2;
    const float* xr = bufc + bloc * 132;
#pragma unroll 8
    for (int k = 0; k < 128; k += 4) {
      float4 w = ld4(wp + k);
      float4 x = ld4(xr + k);
      s0 = fmaf(w.x, x.x, s0); s1 = fmaf(w.y, x.y, s1);
      s2 = fmaf(w.z, x.z, s2); s3 = fmaf(w.w, x.w, s3);
    }
    if (cc + 1 < nch) {
      float* const bufn = ((cc + 1) % 3 == 0) ? xb0 : ((cc + 1) % 3 == 1) ? xb1 : xb2;
      commit(((cc + 1) & 1) ? pfB : pfA, bufn);
    }
    __syncthreads();
  }
  acc += (s0 + s1) + (s2 + s3);

  float* gl = sh + 12672;             // 8 x 32 gate values
  gl[rhat * 32 + bloc] = acc;
  __syncthreads();
  if (tid < 64) {
    const int jh2 = tid >> 5, b2 = tid & 31;
    const int b = bh * 32 + b2;
    const int jj = 2 * up + jh2;
    const float iv = gl[(0 + jh2) * 32 + b2];
    const float fv = gl[(2 + jh2) * 32 + b2];
    const float gv = gl[(4 + jh2) * 32 + b2];
    const float ov = gl[(6 + jh2) * 32 + b2];
    const float cold = cl[(size_t)b * NHH + jj];                 // block-private
    const float cnew = sigf(fv) * cold + sigf(iv) * tanhf(gv);
    const float hnew = sigf(ov) * tanhf(cnew);
    cl[(size_t)b * NHH + jj] = cnew;
    stc(&houtl[(size_t)b * NHH + jj], hnew);                     // cross-block
  }
}

// ---------------- fused attention phase ----------------
// All 512 blocks: role (b, ch). Every block computes q[b] redundantly;
// ch==0 does the cross-chunk combine, posts ctx-ready (per-b MF + per-half
// CTXH), THEN runs the output epilogue — which overlaps the other blocks'
// L0 phase of the next step (no grid barrier after attend).
__device__ void attend_phase(const Params& p, int a, int t, const float* h3,
                             float* sh, int bid, int tid, bool wout) {
  float* wsf = p.wsf;
  unsigned* sync = p.sync;
  const int b  = (bid & 7) * 8 + (bid >> 6);   // siblings of b share an XCD;
  const int ch = (bid >> 3) & 7;               // ch==0 blocks spread over XCDs
  const int sbase = ch * SCHK;

  float* us  = sh + 12928;  // 640: [h3 row | ctx]
  float* qs  = sh + 13568;  // 128
  float* ps  = sh + 13696;  // 256
  float* red = sh + 13952;  // 1056 = 8*132
  float* zs  = sh + 15008;  // 128
  float* lg  = sh + 15136;  // 40

  // stage h3[b] and compute q[b] locally
  if (tid < 128) *(float4*)&us[tid * 4] = ld4c(h3 + (size_t)b * NHH + tid * 4);
  __syncthreads();
  if (tid < NCC) {
    const float* wr = p.wq + (size_t)tid * NHH;
    float s0 = 0.f, s1 = 0.f, s2 = 0.f, s3 = 0.f;
#pragma unroll 8
    for (int k = 0; k < NHH; k += 4) {
      float4 w = ld4(wr + k);
      s0 = fmaf(w.x, us[k],     s0); s1 = fmaf(w.y, us[k + 1], s1);
      s2 = fmaf(w.z, us[k + 2], s2); s3 = fmaf(w.w, us[k + 3], s3);
    }
    qs[tid] = p.bq[tid] + (s0 + s1) + (s2 + s3);
  }
  const int lenb = p.lens[b];
  __syncthreads();

  // energy for my s (kept in a register for the att-out write)
  const int s = sbase + tid;
  const float* kr = p.keys + ((size_t)b * SSS + s) * NCC;
  float e0 = 0.f, e1 = 0.f, e2 = 0.f, e3 = 0.f;
#pragma unroll 8
  for (int c = 0; c < NCC; c += 4) {
    float4 kv = ld4(kr + c);
    e0 = fmaf(qs[c],     kv.x, e0); e1 = fmaf(qs[c + 1], kv.y, e1);
    e2 = fmaf(qs[c + 2], kv.z, e2); e3 = fmaf(qs[c + 3], kv.w, e3);
  }
  float e = (e0 + e1) + (e2 + e3);
  const bool msk = s < lenb;
  e = msk ? e : -1e6f;

  float mx = e;
#pragma unroll
  for (int off = 32; off; off >>= 1) mx = fmaxf(mx, __shfl_xor(mx, off));
  if ((tid & 63) == 0) red[tid >> 6] = mx;
  __syncthreads();
  const float mc = fmaxf(fmaxf(red[0], red[1]), fmaxf(red[2], red[3]));
  const float pv = msk ? expf(e - mc) : 0.f;
  ps[tid] = pv;
  float ls = pv;
#pragma unroll
  for (int off = 32; off; off >>= 1) ls += __shfl_xor(ls, off);
  if ((tid & 63) == 0) red[4 + (tid >> 6)] = ls;
  __syncthreads();
  const float lc = (red[4] + red[5]) + (red[6] + red[7]);

  const int c4 = (tid & 31) << 2;
  const int sg = tid >> 5;
  float r0 = 0.f, r1 = 0.f, r2 = 0.f, r3 = 0.f;
  const float* vb = p.values + ((size_t)b * SSS + sbase + sg * 32) * NCC + c4;
#pragma unroll 4
  for (int i2 = 0; i2 < 32; ++i2) {
    const float pw = ps[sg * 32 + i2];
    float4 vv = ld4(vb + (size_t)i2 * NCC);
    r0 = fmaf(pw, vv.x, r0); r1 = fmaf(pw, vv.y, r1);
    r2 = fmaf(pw, vv.z, r2); r3 = fmaf(pw, vv.w, r3);
  }
  __syncthreads();
  *(float4*)&red[sg * 132 + c4] = make_float4(r0, r1, r2, r3);
  __syncthreads();
  float* pout = wsf + OFF_P + ((size_t)b * NCHK + ch) * 132;
  if (tid < NCC) {
    float sum = 0.f;
#pragma unroll
    for (int sg2 = 0; sg2 < 8; ++sg2) sum += red[sg2 * 132 + tid];
    stc(&pout[4 + tid], sum);
  }
  if (tid == 0) { stc(&pout[0], mc); stc(&pout[1], lc); }
  postflag(&sync[SY_BF(b)]);

  float gm = 0.f, gL = 1.f;
  if (ch == 0) {
    waitflag(&sync[SY_BF(b)], (unsigned)(NCHK * (a + 1)));
    const float* pb = wsf + OFF_P + (size_t)b * NCHK * 132;
    if (tid < 8)       red[tid] = ldc(&pb[tid * 132]);            // m_ch
    else if (tid < 16) red[tid] = ldc(&pb[(tid - 8) * 132 + 1]);  // L_ch
    __syncthreads();
    float m = red[0];
#pragma unroll
    for (int i = 1; i < 8; ++i) m = fmaxf(m, red[i]);
    float L = 0.f;
#pragma unroll
    for (int i = 0; i < 8; ++i) L += red[8 + i] * expf(red[i] - m);
    gm = m; gL = L;
    if (tid < NCC) {
      float v = 0.f;
#pragma unroll
      for (int c2 = 0; c2 < NCHK; ++c2)
        v += ldc(&pb[c2 * 132 + 4 + tid]) * expf(red[c2] - m);
      v /= L;
      stc(&wsf[OFF_CTX + b * NCC + tid], v);
      us[NHH + tid] = v;
    }
    if (tid == 0) { stc(&wsf[OFF_ML + b * 8], m); stc(&wsf[OFF_ML + b * 8 + 1], L); }
    // ctx is now visible: release per-b (for the att-write peers) and the
    // per-half aggregate (for the next step's L0 staging).
    postflag2(&sync[SY_MF(b)], &sync[SY_CTXH(b >> 5)]);
  } else if (wout) {
    waitflag(&sync[SY_MF(b)], (unsigned)(a + 1));
    gm = ldc(&wsf[OFF_ML + b * 8]);
    gL = ldc(&wsf[OFF_ML + b * 8 + 1]);
  }

  if (wout) {
    // ---- epilogue: off the recurrence critical path (overlaps next L0) ----
    float* ao = p.out_att + ((size_t)t * BBB + b) * SSS;
    ao[s] = (msk ? expf(e - gm) : 0.f) / gL;
    if (ch == 0) {
      if (tid < NCC) {
        const float* wr = p.wc + (size_t)tid * (NHH + NCC);
        float s0 = 0.f, s1 = 0.f, s2 = 0.f, s3 = 0.f;
#pragma unroll 8
        for (int k = 0; k < NHH + NCC; k += 4) {
          float4 w = ld4(wr + k);
          s0 = fmaf(w.x, us[k],     s0); s1 = fmaf(w.y, us[k + 1], s1);
          s2 = fmaf(w.z, us[k + 2], s2); s3 = fmaf(w.w, us[k + 3], s3);
        }
        float z = (s0 + s1) + (s2 + s3) + p.bc[tid];
        zs[tid] = (z >= 0.f) ? z : 0.01f * z;
      }
      __syncthreads();
      if (tid < NINP) {
        const float* er = p.emb + tid * NCC;
        float s0 = 0.f, s1 = 0.f, s2 = 0.f, s3 = 0.f;
#pragma unroll 8
        for (int k = 0; k < NCC; k += 4) {
          float4 w = ld4(er + k);
          s0 = fmaf(w.x, zs[k],     s0); s1 = fmaf(w.y, zs[k + 1], s1);
          s2 = fmaf(w.z, zs[k + 2], s2); s3 = fmaf(w.w, zs[k + 3], s3);
        }
        const float lgt = (s0 + s1) + (s2 + s3) + p.bout[tid];
        p.out_logits[((size_t)t * BBB + b) * NINP + tid] = lgt;
        lg[tid] = lgt + gumbel((unsigned)(t * (BBB * NINP) + b * NINP + tid));
      }
      __syncthreads();
      if (tid == 0) {
        float bv = lg[0]; int bix = 0;
        for (int i = 1; i < NINP; ++i) if (lg[i] > bv) { bv = lg[i]; bix = i; }
        p.out_gen[t * BBB + b] = (float)bix;
      }
      __syncthreads();
    }
  }
}

extern "C" __global__ void __launch_bounds__(NTHR, 2)
decoder_kernel(Params p) {
  __shared__ float sh[15232];  // 60,928 B -> 2 blocks/CU (121.9 KB of 160 KB)
  const int bid = blockIdx.x;
  const int tid = threadIdx.x;
  // LSTM role: unit-pair up, batch-half bh. Swizzled so the two batch-half
  // blocks of a unit-pair land on the same XCD (bid and bid+8 -> same XCD
  // under round-robin dispatch) and share weight lines in that L2.
  const int up = (bid & 7) * 32 + (bid >> 4);
  const int bh = (bid >> 3) & 1;
  unsigned epoch = 0;
  unsigned* sync = p.sync;
  float* wsf = p.wsf;

  // init: block (up,bh) owns (b,j) pairs -> init its h (coherent) and c (plain)
  if (tid < 192) {
    const int l = tid >> 6, u = tid & 63;
    const int jh = u >> 5, b2 = u & 31;
    const int b = bh * 32 + b2;
    const int j = 2 * up + jh;
    stc(&wsf[OFF_H + ((size_t)l * BBB + b) * NHH + j], p.h0[l][j]);
    wsf[OFF_C + ((size_t)l * BBB + b) * NHH + j] = p.c0[l][j];
  }
  gbar(sync, epoch, bid);

  attend_phase(p, 0, -1, wsf + OFF_H + 2 * BBB * NHH, sh, bid, tid, false);
  // no grid barrier: L0 waits on the per-half ctx counters instead

  for (int t = 0; t < TTT; ++t) {
    const float* hin = wsf + OFF_H + ((t & 1) ? 3 * BBB * NHH : 0);
    float* hout      = wsf + OFF_H + ((t & 1) ? 0 : 3 * BBB * NHH);

    lstm_layer<0>(p, t, hin, hout, sh, up, bh, tid, sync);
    gbar(sync, epoch, bid);
    lstm_layer<1>(p, t, hin, hout, sh, up, bh, tid, sync);
    gbar(sync, epoch, bid);
    lstm_layer<2>(p, t, hin, hout, sh, up, bh, tid, sync);
    gbar(sync, epoch, bid);
    attend_phase(p, t + 1, t, hout + 2 * BBB * NHH, sh, bid, tid, true);
    // no grid barrier: epilogue overlaps the next step's L0
  }
}

extern "C" void kernel_launch(void* const* d_in, const int* in_sizes, int n_in,
                              void* d_out, int out_size, void* d_ws, size_t ws_size,
                              hipStream_t stream) {
  Params p;
  p.keys   = (const float*)d_in[0];
  p.values = (const float*)d_in[1];
  p.lens   = (const int*)d_in[2];
  p.toks   = (const int*)d_in[3];
  p.emb    = (const float*)d_in[4];
  p.wq     = (const float*)d_in[5];
  p.bq     = (const float*)d_in[6];
  p.wc     = (const float*)d_in[7];
  p.bc     = (const float*)d_in[8];
  p.bout   = (const float*)d_in[9];
  for (int l = 0; l < 3; ++l) {
    p.wih[l] = (const float*)d_in[10 + 6 * l];
    p.whh[l] = (const float*)d_in[11 + 6 * l];
    p.bih[l] = (const float*)d_in[12 + 6 * l];
    p.bhh[l] = (const float*)d_in[13 + 6 * l];
    p.h0[l]  = (const float*)d_in[14 + 6 * l];
    p.c0[l]  = (const float*)d_in[15 + 6 * l];
  }
  float* out = (float*)d_out;
  p.out_logits = out;
  p.out_att    = out + (size_t)TTT * BBB * NINP;
  p.out_gen    = out + (size_t)TTT * BBB * NINP + (size_t)TTT * BBB * SSS;
  p.sync = (unsigned*)d_ws;
  p.wsf  = (float*)((char*)d_ws + 8192);

  hipMemsetAsync(d_ws, 0, 8192, stream);
  decoder_kernel<<<dim3(GDIM), dim3(NTHR), 0, stream>>>(p);
}

// Round 7
// 47550.842 us; speedup vs baseline: 1.1317x; 1.1317x over previous
//
#include <hip/hip_runtime.h>

#define NINP 34
#define NCC  128
#define NHH  512
#define BBB  64
#define SSS  2048
#define TTT  400
#define GEPS 1e-10f

#define GDIM 512
#define NTHR 256
#define NCHK 8        // attention S-chunks
#define SCHK 256      // S per chunk

#define JAX_PARTITIONABLE 1

// ws float offsets (after 8192-byte sync header)
#define OFF_H   0          // h double buffer: 2*3*B*NH = 196608
#define OFF_C   196608     // c: 3*B*NH = 98304
#define OFF_CTX 294912     // B*NC = 8192
#define OFF_ML  303104     // B*8 = 512 (m, L per batch)
#define OFF_P   303616     // B*NCHK*132 = 67584

// sync word layout (2048 uints), all monotonic counters
#define SY_ROOT 0
#define SY_GEN  16
#define SY_LEAFC(l) (256 + 8 * (l))
#define SY_LEAFG(l) (512 + 8 * (l))
#define SY_BF(b)    (1024 + 8 * (b))
#define SY_MF(b)    (1536 + 8 * (b))

struct Params {
  const float* keys; const float* values;
  const int* lens;  const int* toks;
  const float* emb; const float* wq; const float* bq;
  const float* wc;  const float* bc; const float* bout;
  const float* wih[3]; const float* whh[3];
  const float* bih[3]; const float* bhh[3];
  const float* h0[3];  const float* c0[3];
  float* out_logits; float* out_att; float* out_gen;
  float* wsf; unsigned* sync;
};

__device__ __forceinline__ float4 ld4(const float* p) { return *(const float4*)p; }
__device__ __forceinline__ float sigf(float x) { return 1.0f / (1.0f + expf(-x)); }

// ---- relaxed agent-scope ops (sc1, to the IF coherence point). No
// acquire/release (buffer_inv / wbl2 = pathology). Ordering is manual:
// s_waitcnt vmcnt(0) on producer side + compiler barriers.
__device__ __forceinline__ unsigned aload(const unsigned* p) {
  return __hip_atomic_load(p, __ATOMIC_RELAXED, __HIP_MEMORY_SCOPE_AGENT);
}
__device__ __forceinline__ unsigned aadd(unsigned* p, unsigned v) {
  return __hip_atomic_fetch_add(p, v, __ATOMIC_RELAXED, __HIP_MEMORY_SCOPE_AGENT);
}
__device__ __forceinline__ void astore(unsigned* p, unsigned v) {
  __hip_atomic_store(p, v, __ATOMIC_RELAXED, __HIP_MEMORY_SCOPE_AGENT);
}
__device__ __forceinline__ float ldc(const float* p) {
  unsigned u = __hip_atomic_load((const unsigned*)p, __ATOMIC_RELAXED, __HIP_MEMORY_SCOPE_AGENT);
  return __uint_as_float(u);
}
__device__ __forceinline__ void stc(float* p, float v) {
  __hip_atomic_store((unsigned*)p, __float_as_uint(v), __ATOMIC_RELAXED, __HIP_MEMORY_SCOPE_AGENT);
}
__device__ __forceinline__ float4 ld4c(const float* p) {
  unsigned long long a = __hip_atomic_load((const unsigned long long*)p,
                                           __ATOMIC_RELAXED, __HIP_MEMORY_SCOPE_AGENT);
  unsigned long long b = __hip_atomic_load(((const unsigned long long*)p) + 1,
                                           __ATOMIC_RELAXED, __HIP_MEMORY_SCOPE_AGENT);
  float4 r;
  r.x = __uint_as_float((unsigned)a); r.y = __uint_as_float((unsigned)(a >> 32));
  r.z = __uint_as_float((unsigned)b); r.w = __uint_as_float((unsigned)(b >> 32));
  return r;
}
__device__ __forceinline__ void wait_vm0() {
  asm volatile("s_waitcnt vmcnt(0)" ::: "memory");
}
__device__ __forceinline__ void cbar() { asm volatile("" ::: "memory"); }

// Tree grid barrier: 32 leaves x 16 blocks. Release fans out via per-leaf
// generation words so no line has >32 pollers.
__device__ void gbar(unsigned* sync, unsigned& epoch, int bid) {
  wait_vm0();
  __syncthreads();
  if (threadIdx.x == 0) {
    epoch++;
    const int leaf = bid >> 4;
    const bool leader = (bid & 15) == 0;
    if (aadd(&sync[SY_LEAFC(leaf)], 1u) == 16u * epoch - 1u) {
      if (aadd(&sync[SY_ROOT], 1u) == 32u * epoch - 1u)
        astore(&sync[SY_GEN], epoch);
    }
    if (leader) {
      while (aload(&sync[SY_GEN]) < epoch) __builtin_amdgcn_s_sleep(1);
      astore(&sync[SY_LEAFG(leaf)], epoch);
    } else {
      while (aload(&sync[SY_LEAFG(leaf)]) < epoch) __builtin_amdgcn_s_sleep(1);
    }
  }
  __syncthreads();
  cbar();
}

__device__ __forceinline__ void waitflag(unsigned* p, unsigned target) {
  if (threadIdx.x == 0) {
    while (aload(p) < target) __builtin_amdgcn_s_sleep(2);
  }
  __syncthreads();
  cbar();
}
__device__ __forceinline__ void postflag(unsigned* p) {
  wait_vm0();
  __syncthreads();
  if (threadIdx.x == 0) aadd(p, 1u);
}

// ---------------- Threefry2x32-20, jax.random.key(1) ----------------
__device__ __forceinline__ void tfr(unsigned& x0, unsigned& x1, int r) {
  x0 += x1; x1 = (x1 << r) | (x1 >> (32 - r)); x1 ^= x0;
}
__device__ unsigned threefry_bits(unsigned idx) {
  const unsigned k0 = 0u, k1 = 1u;
  const unsigned k2 = 0x1BD11BDAu ^ k0 ^ k1;
#if JAX_PARTITIONABLE
  unsigned x0 = 0u, x1 = idx;
#else
  const unsigned half = (TTT * BBB * NINP) / 2;
  const bool lo = idx < half;
  unsigned x0 = lo ? idx : idx - half;
  unsigned x1 = lo ? idx + half : idx;
#endif
  x0 += k0; x1 += k1;
  tfr(x0,x1,13); tfr(x0,x1,15); tfr(x0,x1,26); tfr(x0,x1,6);
  x0 += k1; x1 += k2 + 1u;
  tfr(x0,x1,17); tfr(x0,x1,29); tfr(x0,x1,16); tfr(x0,x1,24);
  x0 += k2; x1 += k0 + 2u;
  tfr(x0,x1,13); tfr(x0,x1,15); tfr(x0,x1,26); tfr(x0,x1,6);
  x0 += k0; x1 += k1 + 3u;
  tfr(x0,x1,17); tfr(x0,x1,29); tfr(x0,x1,16); tfr(x0,x1,24);
  x0 += k1; x1 += k2 + 4u;
  tfr(x0,x1,13); tfr(x0,x1,15); tfr(x0,x1,26); tfr(x0,x1,6);
  x0 += k2; x1 += k0 + 5u;
#if JAX_PARTITIONABLE
  return x0 ^ x1;
#else
  return lo ? x0 : x1;
#endif
}
__device__ __forceinline__ float gumbel(unsigned idx) {
  unsigned bits = threefry_bits(idx);
  float u = __uint_as_float((bits >> 9) | 0x3f800000u) - 1.0f;
  u = fmaxf(u, 0.0f);
  return -logf(GEPS - logf(u + GEPS));
}

// ---------------- LSTM layer phase ----------------
// Block = (unit-pair up, batch-half bh): 8 gate-rows x 32 batches.
// Staging is double-buffered with register prefetch (chunk cc+1 loads are
// in flight while chunk cc's FMAs run).  [r3 structure — known good]
template<int L>
__device__ void lstm_layer(const Params& p, int t, const float* hin, float* hout,
                           float* sh, int up, int bh, int tid) {
  const float* hin_l = hin + L * BBB * NHH + (size_t)bh * 32 * NHH;
  float* houtl = hout + L * BBB * NHH;
  float* cl = p.wsf + OFF_C + L * BBB * NHH;
  const float* xlow = (L == 0) ? (const float*)0
                               : (hout + (L - 1) * BBB * NHH + (size_t)bh * 32 * NHH);

  const int insz = (L == 0) ? (2 * NCC) : NHH;
  const int nx = insz >> 7;
  const int nch = nx + 4;

  const int rhat = tid >> 5;          // 0..7 : (g = rhat>>1, jh = rhat&1)
  const int bloc = tid & 31;          // 0..31
  const int g = rhat >> 1, jh = rhat & 1;
  const int j = 2 * up + jh;
  const int row = g * NHH + j;
  const float* wr  = p.wih[L] + (size_t)row * insz;
  const float* wr2 = p.whh[L] + (size_t)row * NHH;

  float* xb0 = sh;            // 32 x 132
  float* xb1 = sh + 4224;
  const int kk  = (tid & 31) << 2;    // 0..124
  const int rb0 = tid >> 5;           // 0..7

  float4 pf[4];
  auto issue = [&](int cc) {
#pragma unroll
    for (int it = 0; it < 4; ++it) {
      const int rb = rb0 + (it << 3);        // local batch 0..31
      const int gb = bh * 32 + rb;           // global batch
      const bool isx = cc < nx;
      const int off = (isx ? cc : cc - nx) << 7;
      if (L == 0) {
        if (isx) pf[it] = (cc == 0)
            ? ld4(p.emb + (size_t)p.toks[gb * TTT + t] * NCC + kk)   // read-only
            : ld4c(p.wsf + OFF_CTX + gb * NCC + kk);                 // kernel-written
        else pf[it] = ld4c(hin_l + (size_t)rb * NHH + off + kk);
      } else {
        pf[it] = isx ? ld4c(xlow + (size_t)rb * NHH + off + kk)
                     : ld4c(hin_l + (size_t)rb * NHH + off + kk);
      }
    }
  };
  auto commit = [&](float* buf) {
#pragma unroll
    for (int it = 0; it < 4; ++it)
      *(float4*)&buf[(rb0 + (it << 3)) * 132 + kk] = pf[it];
  };

  float acc = p.bih[L][row] + p.bhh[L][row];
  float s0 = 0.f, s1 = 0.f, s2 = 0.f, s3 = 0.f;

  issue(0);
  commit(xb0);
  __syncthreads();
  for (int cc = 0; cc < nch; ++cc) {
    if (cc + 1 < nch) issue(cc + 1);
    const bool isx = cc < nx;
    const int off = (isx ? cc : cc - nx) << 7;
    const float* wp = (isx ? wr : wr2) + off;
    const float* xr = ((cc & 1) ? xb1 : xb0) + bloc * 132;
#pragma unroll 8
    for (int k = 0; k < 128; k += 4) {
      float4 w = ld4(wp + k);
      float4 x = ld4(xr + k);
      s0 = fmaf(w.x, x.x, s0); s1 = fmaf(w.y, x.y, s1);
      s2 = fmaf(w.z, x.z, s2); s3 = fmaf(w.w, x.w, s3);
    }
    if (cc + 1 < nch) commit((cc & 1) ? xb0 : xb1);
    __syncthreads();
  }
  acc += (s0 + s1) + (s2 + s3);

  float* gl = sh + 8448;              // 8 x 32 gate values
  gl[rhat * 32 + bloc] = acc;
  __syncthreads();
  if (tid < 64) {
    const int jh2 = tid >> 5, b2 = tid & 31;
    const int b = bh * 32 + b2;
    const int jj = 2 * up + jh2;
    const float iv = gl[(0 + jh2) * 32 + b2];
    const float fv = gl[(2 + jh2) * 32 + b2];
    const float gv = gl[(4 + jh2) * 32 + b2];
    const float ov = gl[(6 + jh2) * 32 + b2];
    const float cold = cl[(size_t)b * NHH + jj];                 // block-private
    const float cnew = sigf(fv) * cold + sigf(iv) * tanhf(gv);
    const float hnew = sigf(ov) * tanhf(cnew);
    cl[(size_t)b * NHH + jj] = cnew;
    stc(&houtl[(size_t)b * NHH + jj], hnew);                     // cross-block
  }
}

// ---------------- fused attention phase ----------------
// All 512 blocks: role (b, ch). Every block computes q[b] redundantly;
// ch==0 does the cross-chunk combine + z/logits.
// NEW (r7): masked-position skip — threads with s >= lens[b] skip the K dot
// (e = -1e6 exactly as before) and the V accumulation loop is bounded by the
// number of valid rows in the sub-chunk (skipped rows have pv == 0 exactly).
// Bit-identical results; ~25% less K/V traffic and attend FMA on average.
__device__ void attend_phase(const Params& p, int a, int t, const float* h3,
                             float* sh, int bid, int tid, bool wout) {
  float* wsf = p.wsf;
  unsigned* sync = p.sync;
  const int b  = (bid & 7) * 8 + (bid >> 6);   // siblings of b share an XCD;
  const int ch = (bid >> 3) & 7;               // ch==0 blocks spread over XCDs
  const int sbase = ch * SCHK;

  float* us  = sh + 8704;   // 640: [h3 row | ctx]
  float* qs  = sh + 9344;   // 128
  float* ps  = sh + 9472;   // 256
  float* red = sh + 9728;   // 1056 = 8*132
  float* zs  = sh + 10784;  // 128
  float* lg  = sh + 10912;  // 40

  // stage h3[b] and compute q[b] locally
  if (tid < 128) *(float4*)&us[tid * 4] = ld4c(h3 + (size_t)b * NHH + tid * 4);
  __syncthreads();
  if (tid < NCC) {
    const float* wr = p.wq + (size_t)tid * NHH;
    float s0 = 0.f, s1 = 0.f, s2 = 0.f, s3 = 0.f;
#pragma unroll 8
    for (int k = 0; k < NHH; k += 4) {
      float4 w = ld4(wr + k);
      s0 = fmaf(w.x, us[k],     s0); s1 = fmaf(w.y, us[k + 1], s1);
      s2 = fmaf(w.z, us[k + 2], s2); s3 = fmaf(w.w, us[k + 3], s3);
    }
    qs[tid] = p.bq[tid] + (s0 + s1) + (s2 + s3);
  }
  const int lenb = p.lens[b];
  __syncthreads();

  // energy for my s (kept in a register for the att-out write)
  const int s = sbase + tid;
  const bool msk = s < lenb;
  float e = -1e6f;
  if (msk) {
    const float* kr = p.keys + ((size_t)b * SSS + s) * NCC;
    float e0 = 0.f, e1 = 0.f, e2 = 0.f, e3 = 0.f;
#pragma unroll 8
    for (int c = 0; c < NCC; c += 4) {
      float4 kv = ld4(kr + c);
      e0 = fmaf(qs[c],     kv.x, e0); e1 = fmaf(qs[c + 1], kv.y, e1);
      e2 = fmaf(qs[c + 2], kv.z, e2); e3 = fmaf(qs[c + 3], kv.w, e3);
    }
    e = (e0 + e1) + (e2 + e3);
  }

  float mx = e;
#pragma unroll
  for (int off = 32; off; off >>= 1) mx = fmaxf(mx, __shfl_xor(mx, off));
  if ((tid & 63) == 0) red[tid >> 6] = mx;
  __syncthreads();
  const float mc = fmaxf(fmaxf(red[0], red[1]), fmaxf(red[2], red[3]));
  const float pv = msk ? expf(e - mc) : 0.f;
  ps[tid] = pv;
  float ls = pv;
#pragma unroll
  for (int off = 32; off; off >>= 1) ls += __shfl_xor(ls, off);
  if ((tid & 63) == 0) red[4 + (tid >> 6)] = ls;
  __syncthreads();
  const float lc = (red[4] + red[5]) + (red[6] + red[7]);

  const int c4 = (tid & 31) << 2;
  const int sg = tid >> 5;
  float r0 = 0.f, r1 = 0.f, r2 = 0.f, r3 = 0.f;
  // rows beyond lenb have pv == 0 exactly -> skipping them is bit-identical
  const int nval = min(max(lenb - sbase - sg * 32, 0), 32);
  const float* vb = p.values + ((size_t)b * SSS + sbase + sg * 32) * NCC + c4;
#pragma unroll 4
  for (int i2 = 0; i2 < nval; ++i2) {
    const float pw = ps[sg * 32 + i2];
    float4 vv = ld4(vb + (size_t)i2 * NCC);
    r0 = fmaf(pw, vv.x, r0); r1 = fmaf(pw, vv.y, r1);
    r2 = fmaf(pw, vv.z, r2); r3 = fmaf(pw, vv.w, r3);
  }
  __syncthreads();
  *(float4*)&red[sg * 132 + c4] = make_float4(r0, r1, r2, r3);
  __syncthreads();
  float* pout = wsf + OFF_P + ((size_t)b * NCHK + ch) * 132;
  if (tid < NCC) {
    float sum = 0.f;
#pragma unroll
    for (int sg2 = 0; sg2 < 8; ++sg2) sum += red[sg2 * 132 + tid];
    stc(&pout[2 + tid], sum);
  }
  if (tid == 0) { stc(&pout[0], mc); stc(&pout[1], lc); }
  postflag(&sync[SY_BF(b)]);

  float gm = 0.f, gL = 1.f;
  if (ch == 0) {
    waitflag(&sync[SY_BF(b)], (unsigned)(NCHK * (a + 1)));
    const float* pb = wsf + OFF_P + (size_t)b * NCHK * 132;
    if (tid < 8)       red[tid] = ldc(&pb[tid * 132]);            // m_ch
    else if (tid < 16) red[tid] = ldc(&pb[(tid - 8) * 132 + 1]);  // L_ch
    __syncthreads();
    float m = red[0];
#pragma unroll
    for (int i = 1; i < 8; ++i) m = fmaxf(m, red[i]);
    float L = 0.f;
#pragma unroll
    for (int i = 0; i < 8; ++i) L += red[8 + i] * expf(red[i] - m);
    gm = m; gL = L;
    if (tid < NCC) {
      float v = 0.f;
#pragma unroll
      for (int c2 = 0; c2 < NCHK; ++c2)
        v += ldc(&pb[c2 * 132 + 2 + tid]) * expf(red[c2] - m);
      v /= L;
      stc(&wsf[OFF_CTX + b * NCC + tid], v);
      us[NHH + tid] = v;
    }
    if (tid == 0) { stc(&wsf[OFF_ML + b * 8], m); stc(&wsf[OFF_ML + b * 8 + 1], L); }
    postflag(&sync[SY_MF(b)]);
  } else if (wout) {
    waitflag(&sync[SY_MF(b)], (unsigned)(a + 1));
    gm = ldc(&wsf[OFF_ML + b * 8]);
    gL = ldc(&wsf[OFF_ML + b * 8 + 1]);
  }

  if (wout) {
    float* ao = p.out_att + ((size_t)t * BBB + b) * SSS;
    ao[s] = (msk ? expf(e - gm) : 0.f) / gL;
    if (ch == 0) {
      if (tid < NCC) {
        const float* wr = p.wc + (size_t)tid * (NHH + NCC);
        float s0 = 0.f, s1 = 0.f, s2 = 0.f, s3 = 0.f;
#pragma unroll 8
        for (int k = 0; k < NHH + NCC; k += 4) {
          float4 w = ld4(wr + k);
          s0 = fmaf(w.x, us[k],     s0); s1 = fmaf(w.y, us[k + 1], s1);
          s2 = fmaf(w.z, us[k + 2], s2); s3 = fmaf(w.w, us[k + 3], s3);
        }
        float z = (s0 + s1) + (s2 + s3) + p.bc[tid];
        zs[tid] = (z >= 0.f) ? z : 0.01f * z;
      }
      __syncthreads();
      if (tid < NINP) {
        const float* er = p.emb + tid * NCC;
        float s0 = 0.f, s1 = 0.f, s2 = 0.f, s3 = 0.f;
#pragma unroll 8
        for (int k = 0; k < NCC; k += 4) {
          float4 w = ld4(er + k);
          s0 = fmaf(w.x, zs[k],     s0); s1 = fmaf(w.y, zs[k + 1], s1);
          s2 = fmaf(w.z, zs[k + 2], s2); s3 = fmaf(w.w, zs[k + 3], s3);
        }
        const float lgt = (s0 + s1) + (s2 + s3) + p.bout[tid];
        p.out_logits[((size_t)t * BBB + b) * NINP + tid] = lgt;
        lg[tid] = lgt + gumbel((unsigned)(t * (BBB * NINP) + b * NINP + tid));
      }
      __syncthreads();
      if (tid == 0) {
        float bv = lg[0]; int bix = 0;
        for (int i = 1; i < NINP; ++i) if (lg[i] > bv) { bv = lg[i]; bix = i; }
        p.out_gen[t * BBB + b] = (float)bix;
      }
      __syncthreads();
    }
  }
}

extern "C" __global__ void __launch_bounds__(NTHR, 2)
decoder_kernel(Params p) {
  __shared__ float sh[11008];  // 44,032 B -> 2 blocks/CU
  const int bid = blockIdx.x;
  const int tid = threadIdx.x;
  // LSTM role: unit-pair up, batch-half bh. Swizzled so the two batch-half
  // blocks of a unit-pair land on the same XCD (bid and bid+8 -> same XCD
  // under round-robin dispatch) and share weight lines in that L2.
  const int up = (bid & 7) * 32 + (bid >> 4);
  const int bh = (bid >> 3) & 1;
  unsigned epoch = 0;
  unsigned* sync = p.sync;
  float* wsf = p.wsf;

  // init: block (up,bh) owns (b,j) pairs -> init its h (coherent) and c (plain)
  if (tid < 192) {
    const int l = tid >> 6, u = tid & 63;
    const int jh = u >> 5, b2 = u & 31;
    const int b = bh * 32 + b2;
    const int j = 2 * up + jh;
    stc(&wsf[OFF_H + ((size_t)l * BBB + b) * NHH + j], p.h0[l][j]);
    wsf[OFF_C + ((size_t)l * BBB + b) * NHH + j] = p.c0[l][j];
  }
  gbar(sync, epoch, bid);

  attend_phase(p, 0, -1, wsf + OFF_H + 2 * BBB * NHH, sh, bid, tid, false);
  gbar(sync, epoch, bid);

  for (int t = 0; t < TTT; ++t) {
    const float* hin = wsf + OFF_H + ((t & 1) ? 3 * BBB * NHH : 0);
    float* hout      = wsf + OFF_H + ((t & 1) ? 0 : 3 * BBB * NHH);

    lstm_layer<0>(p, t, hin, hout, sh, up, bh, tid);
    gbar(sync, epoch, bid);
    lstm_layer<1>(p, t, hin, hout, sh, up, bh, tid);
    gbar(sync, epoch, bid);
    lstm_layer<2>(p, t, hin, hout, sh, up, bh, tid);
    gbar(sync, epoch, bid);
    attend_phase(p, t + 1, t, hout + 2 * BBB * NHH, sh, bid, tid, true);
    gbar(sync, epoch, bid);
  }
}

extern "C" void kernel_launch(void* const* d_in, const int* in_sizes, int n_in,
                              void* d_out, int out_size, void* d_ws, size_t ws_size,
                              hipStream_t stream) {
  Params p;
  p.keys   = (const float*)d_in[0];
  p.values = (const float*)d_in[1];
  p.lens   = (const int*)d_in[2];
  p.toks   = (const int*)d_in[3];
  p.emb    = (const float*)d_in[4];
  p.wq     = (const float*)d_in[5];
  p.bq     = (const float*)d_in[6];
  p.wc     = (const float*)d_in[7];
  p.bc     = (const float*)d_in[8];
  p.bout   = (const float*)d_in[9];
  for (int l = 0; l < 3; ++l) {
    p.wih[l] = (const float*)d_in[10 + 6 * l];
    p.whh[l] = (const float*)d_in[11 + 6 * l];
    p.bih[l] = (const float*)d_in[12 + 6 * l];
    p.bhh[l] = (const float*)d_in[13 + 6 * l];
    p.h0[l]  = (const float*)d_in[14 + 6 * l];
    p.c0[l]  = (const float*)d_in[15 + 6 * l];
  }
  float* out = (float*)d_out;
  p.out_logits = out;
  p.out_att    = out + (size_t)TTT * BBB * NINP;
  p.out_gen    = out + (size_t)TTT * BBB * NINP + (size_t)TTT * BBB * SSS;
  p.sync = (unsigned*)d_ws;
  p.wsf  = (float*)((char*)d_ws + 8192);

  hipMemsetAsync(d_ws, 0, 8192, stream);
  decoder_kernel<<<dim3(GDIM), dim3(NTHR), 0, stream>>>(p);
}

// Round 8
// 43234.857 us; speedup vs baseline: 1.2447x; 1.0998x over previous
//
#include <hip/hip_runtime.h>

#define NINP 34
#define NCC  128
#define NHH  512
#define BBB  64
#define SSS  2048
#define TTT  400
#define GEPS 1e-10f

#define GDIM 512
#define NTHR 256
#define NCHK 8        // attention S-chunks
#define SCHK 256      // S per chunk

#define JAX_PARTITIONABLE 1

// ws float offsets (after 8192-byte sync header)
#define OFF_H   0          // h double buffer: 2*3*B*NH = 196608
#define OFF_C   196608     // c: 3*B*NH = 98304
#define OFF_CTX 294912     // B*NC = 8192
#define OFF_ML  303104     // B*8 = 512 (m, L per batch)
#define OFF_P   303616     // B*NCHK*132 = 67584

// sync word layout (2048 uints), all monotonic counters
#define SY_ROOT 0
#define SY_GEN  16
#define SY_LEAFC(l) (256 + 8 * (l))
#define SY_LEAFG(l) (512 + 8 * (l))
#define SY_BF(b)    (1024 + 8 * (b))
#define SY_MF(b)    (1536 + 8 * (b))

struct Params {
  const float* keys; const float* values;
  const int* lens;  const int* toks;
  const float* emb; const float* wq; const float* bq;
  const float* wc;  const float* bc; const float* bout;
  const float* wih[3]; const float* whh[3];
  const float* bih[3]; const float* bhh[3];
  const float* h0[3];  const float* c0[3];
  float* out_logits; float* out_att; float* out_gen;
  float* wsf; unsigned* sync;
};

__device__ __forceinline__ float4 ld4(const float* p) { return *(const float4*)p; }
__device__ __forceinline__ float sigf(float x) { return 1.0f / (1.0f + expf(-x)); }

// ---- relaxed agent-scope ops (sc1, to the IF coherence point). No
// acquire/release (buffer_inv / wbl2 = pathology). Ordering is manual:
// s_waitcnt vmcnt(0) on producer side + compiler barriers.
__device__ __forceinline__ unsigned aload(const unsigned* p) {
  return __hip_atomic_load(p, __ATOMIC_RELAXED, __HIP_MEMORY_SCOPE_AGENT);
}
__device__ __forceinline__ unsigned aadd(unsigned* p, unsigned v) {
  return __hip_atomic_fetch_add(p, v, __ATOMIC_RELAXED, __HIP_MEMORY_SCOPE_AGENT);
}
__device__ __forceinline__ void astore(unsigned* p, unsigned v) {
  __hip_atomic_store(p, v, __ATOMIC_RELAXED, __HIP_MEMORY_SCOPE_AGENT);
}
__device__ __forceinline__ float ldc(const float* p) {
  unsigned u = __hip_atomic_load((const unsigned*)p, __ATOMIC_RELAXED, __HIP_MEMORY_SCOPE_AGENT);
  return __uint_as_float(u);
}
__device__ __forceinline__ void stc(float* p, float v) {
  __hip_atomic_store((unsigned*)p, __float_as_uint(v), __ATOMIC_RELAXED, __HIP_MEMORY_SCOPE_AGENT);
}
__device__ __forceinline__ float4 ld4c(const float* p) {
  unsigned long long a = __hip_atomic_load((const unsigned long long*)p,
                                           __ATOMIC_RELAXED, __HIP_MEMORY_SCOPE_AGENT);
  unsigned long long b = __hip_atomic_load(((const unsigned long long*)p) + 1,
                                           __ATOMIC_RELAXED, __HIP_MEMORY_SCOPE_AGENT);
  float4 r;
  r.x = __uint_as_float((unsigned)a); r.y = __uint_as_float((unsigned)(a >> 32));
  r.z = __uint_as_float((unsigned)b); r.w = __uint_as_float((unsigned)(b >> 32));
  return r;
}
__device__ __forceinline__ void wait_vm0() {
  asm volatile("s_waitcnt vmcnt(0)" ::: "memory");
}
__device__ __forceinline__ void cbar() { asm volatile("" ::: "memory"); }

// Tree grid barrier: 32 leaves x 16 blocks. Release fans out via per-leaf
// generation words so no line has >32 pollers.
__device__ void gbar(unsigned* sync, unsigned& epoch, int bid) {
  wait_vm0();
  __syncthreads();
  if (threadIdx.x == 0) {
    epoch++;
    const int leaf = bid >> 4;
    const bool leader = (bid & 15) == 0;
    if (aadd(&sync[SY_LEAFC(leaf)], 1u) == 16u * epoch - 1u) {
      if (aadd(&sync[SY_ROOT], 1u) == 32u * epoch - 1u)
        astore(&sync[SY_GEN], epoch);
    }
    if (leader) {
      while (aload(&sync[SY_GEN]) < epoch) __builtin_amdgcn_s_sleep(1);
      astore(&sync[SY_LEAFG(leaf)], epoch);
    } else {
      while (aload(&sync[SY_LEAFG(leaf)]) < epoch) __builtin_amdgcn_s_sleep(1);
    }
  }
  __syncthreads();
  cbar();
}

__device__ __forceinline__ void waitflag(unsigned* p, unsigned target) {
  if (threadIdx.x == 0) {
    while (aload(p) < target) __builtin_amdgcn_s_sleep(2);
  }
  __syncthreads();
  cbar();
}
__device__ __forceinline__ void postflag(unsigned* p) {
  wait_vm0();
  __syncthreads();
  if (threadIdx.x == 0) aadd(p, 1u);
}

// ---------------- Threefry2x32-20, jax.random.key(1) ----------------
__device__ __forceinline__ void tfr(unsigned& x0, unsigned& x1, int r) {
  x0 += x1; x1 = (x1 << r) | (x1 >> (32 - r)); x1 ^= x0;
}
__device__ unsigned threefry_bits(unsigned idx) {
  const unsigned k0 = 0u, k1 = 1u;
  const unsigned k2 = 0x1BD11BDAu ^ k0 ^ k1;
#if JAX_PARTITIONABLE
  unsigned x0 = 0u, x1 = idx;
#else
  const unsigned half = (TTT * BBB * NINP) / 2;
  const bool lo = idx < half;
  unsigned x0 = lo ? idx : idx - half;
  unsigned x1 = lo ? idx + half : idx;
#endif
  x0 += k0; x1 += k1;
  tfr(x0,x1,13); tfr(x0,x1,15); tfr(x0,x1,26); tfr(x0,x1,6);
  x0 += k1; x1 += k2 + 1u;
  tfr(x0,x1,17); tfr(x0,x1,29); tfr(x0,x1,16); tfr(x0,x1,24);
  x0 += k2; x1 += k0 + 2u;
  tfr(x0,x1,13); tfr(x0,x1,15); tfr(x0,x1,26); tfr(x0,x1,6);
  x0 += k0; x1 += k1 + 3u;
  tfr(x0,x1,17); tfr(x0,x1,29); tfr(x0,x1,16); tfr(x0,x1,24);
  x0 += k1; x1 += k2 + 4u;
  tfr(x0,x1,13); tfr(x0,x1,15); tfr(x0,x1,26); tfr(x0,x1,6);
  x0 += k2; x1 += k0 + 5u;
#if JAX_PARTITIONABLE
  return x0 ^ x1;
#else
  return lo ? x0 : x1;
#endif
}
__device__ __forceinline__ float gumbel(unsigned idx) {
  unsigned bits = threefry_bits(idx);
  float u = __uint_as_float((bits >> 9) | 0x3f800000u) - 1.0f;
  u = fmaxf(u, 0.0f);
  return -logf(GEPS - logf(u + GEPS));
}

// ---------------- LSTM layer phase ----------------
// r8 re-block: block = (unit-group ug: 8 units, batch-octant boct: 8 batches)
// -> 32 gate-rows x 8 batches = 256 dots, one per thread.
// vs r7 (2 units x 32 batches): coherent x-staging per block drops 4x
// (16 KB -> 4 KB per chunk); weight reads grow 4x but are plain L1/L2-cached
// loads (the 8 blocks sharing ug sit on one XCD via the mod-8 swizzle, so
// weights are L2-resident). Dot accumulation order unchanged -> bit-identical.
template<int L>
__device__ void lstm_layer(const Params& p, int t, const float* hin, float* hout,
                           float* sh, int ug, int boct, int tid) {
  const float* hin_l = hin + L * BBB * NHH + (size_t)boct * 8 * NHH;
  float* houtl = hout + L * BBB * NHH;
  float* cl = p.wsf + OFF_C + L * BBB * NHH;
  const float* xlow = (L == 0) ? (const float*)0
                               : (hout + (L - 1) * BBB * NHH + (size_t)boct * 8 * NHH);

  const int insz = (L == 0) ? (2 * NCC) : NHH;
  const int nx = insz >> 7;
  const int nch = nx + 4;

  const int rhat = tid >> 3;          // 0..31 : gate-row = g*8 + jl
  const int bloc = tid & 7;           // 0..7  : local batch
  const int g = rhat >> 3, jl = rhat & 7;
  const int j = ug * 8 + jl;
  const int row = g * NHH + j;
  const float* wr  = p.wih[L] + (size_t)row * insz;
  const float* wr2 = p.whh[L] + (size_t)row * NHH;

  float* xb0 = sh;            // 8 x 132
  float* xb1 = sh + 1056;
  const int kk  = (tid & 31) << 2;    // 0..124
  const int rb0 = tid >> 5;           // 0..7 : one staged row per thread

  float4 pf;
  auto issue = [&](int cc) {
    const int rb = rb0;                    // local batch 0..7
    const int gb = boct * 8 + rb;          // global batch
    const bool isx = cc < nx;
    const int off = (isx ? cc : cc - nx) << 7;
    if (L == 0) {
      if (isx) pf = (cc == 0)
          ? ld4(p.emb + (size_t)p.toks[gb * TTT + t] * NCC + kk)   // read-only
          : ld4c(p.wsf + OFF_CTX + gb * NCC + kk);                 // kernel-written
      else pf = ld4c(hin_l + (size_t)rb * NHH + off + kk);
    } else {
      pf = isx ? ld4c(xlow + (size_t)rb * NHH + off + kk)
               : ld4c(hin_l + (size_t)rb * NHH + off + kk);
    }
  };
  auto commit = [&](float* buf) {
    *(float4*)&buf[rb0 * 132 + kk] = pf;
  };

  float acc = p.bih[L][row] + p.bhh[L][row];
  float s0 = 0.f, s1 = 0.f, s2 = 0.f, s3 = 0.f;

  issue(0);
  commit(xb0);
  __syncthreads();
  for (int cc = 0; cc < nch; ++cc) {
    if (cc + 1 < nch) issue(cc + 1);
    const bool isx = cc < nx;
    const int off = (isx ? cc : cc - nx) << 7;
    const float* wp = (isx ? wr : wr2) + off;
    const float* xr = ((cc & 1) ? xb1 : xb0) + bloc * 132;
#pragma unroll 8
    for (int k = 0; k < 128; k += 4) {
      float4 w = ld4(wp + k);
      float4 x = ld4(xr + k);
      s0 = fmaf(w.x, x.x, s0); s1 = fmaf(w.y, x.y, s1);
      s2 = fmaf(w.z, x.z, s2); s3 = fmaf(w.w, x.w, s3);
    }
    if (cc + 1 < nch) commit((cc & 1) ? xb0 : xb1);
    __syncthreads();
  }
  acc += (s0 + s1) + (s2 + s3);

  float* gl = sh + 2112;              // 32 x 8 gate values
  gl[rhat * 8 + bloc] = acc;
  __syncthreads();
  if (tid < 64) {
    const int jl2 = tid >> 3, bl = tid & 7;
    const int b = boct * 8 + bl;
    const int jj = ug * 8 + jl2;
    const float iv = gl[(0  + jl2) * 8 + bl];
    const float fv = gl[(8  + jl2) * 8 + bl];
    const float gv = gl[(16 + jl2) * 8 + bl];
    const float ov = gl[(24 + jl2) * 8 + bl];
    const float cold = cl[(size_t)b * NHH + jj];                 // block-private
    const float cnew = sigf(fv) * cold + sigf(iv) * tanhf(gv);
    const float hnew = sigf(ov) * tanhf(cnew);
    cl[(size_t)b * NHH + jj] = cnew;
    stc(&houtl[(size_t)b * NHH + jj], hnew);                     // cross-block
  }
}

// ---------------- fused attention phase ----------------
// All 512 blocks: role (b, ch). Every block computes q[b] redundantly;
// ch==0 does the cross-chunk combine + z/logits.
// Masked-position skip (r7): bit-identical, ~25% less K/V traffic.
__device__ void attend_phase(const Params& p, int a, int t, const float* h3,
                             float* sh, int bid, int tid, bool wout) {
  float* wsf = p.wsf;
  unsigned* sync = p.sync;
  const int b  = (bid & 7) * 8 + (bid >> 6);   // siblings of b share an XCD;
  const int ch = (bid >> 3) & 7;               // ch==0 blocks spread over XCDs
  const int sbase = ch * SCHK;

  float* us  = sh + 8704;   // 640: [h3 row | ctx]
  float* qs  = sh + 9344;   // 128
  float* ps  = sh + 9472;   // 256
  float* red = sh + 9728;   // 1056 = 8*132
  float* zs  = sh + 10784;  // 128
  float* lg  = sh + 10912;  // 40

  // stage h3[b] and compute q[b] locally
  if (tid < 128) *(float4*)&us[tid * 4] = ld4c(h3 + (size_t)b * NHH + tid * 4);
  __syncthreads();
  if (tid < NCC) {
    const float* wr = p.wq + (size_t)tid * NHH;
    float s0 = 0.f, s1 = 0.f, s2 = 0.f, s3 = 0.f;
#pragma unroll 8
    for (int k = 0; k < NHH; k += 4) {
      float4 w = ld4(wr + k);
      s0 = fmaf(w.x, us[k],     s0); s1 = fmaf(w.y, us[k + 1], s1);
      s2 = fmaf(w.z, us[k + 2], s2); s3 = fmaf(w.w, us[k + 3], s3);
    }
    qs[tid] = p.bq[tid] + (s0 + s1) + (s2 + s3);
  }
  const int lenb = p.lens[b];
  __syncthreads();

  // energy for my s (kept in a register for the att-out write)
  const int s = sbase + tid;
  const bool msk = s < lenb;
  float e = -1e6f;
  if (msk) {
    const float* kr = p.keys + ((size_t)b * SSS + s) * NCC;
    float e0 = 0.f, e1 = 0.f, e2 = 0.f, e3 = 0.f;
#pragma unroll 8
    for (int c = 0; c < NCC; c += 4) {
      float4 kv = ld4(kr + c);
      e0 = fmaf(qs[c],     kv.x, e0); e1 = fmaf(qs[c + 1], kv.y, e1);
      e2 = fmaf(qs[c + 2], kv.z, e2); e3 = fmaf(qs[c + 3], kv.w, e3);
    }
    e = (e0 + e1) + (e2 + e3);
  }

  float mx = e;
#pragma unroll
  for (int off = 32; off; off >>= 1) mx = fmaxf(mx, __shfl_xor(mx, off));
  if ((tid & 63) == 0) red[tid >> 6] = mx;
  __syncthreads();
  const float mc = fmaxf(fmaxf(red[0], red[1]), fmaxf(red[2], red[3]));
  const float pv = msk ? expf(e - mc) : 0.f;
  ps[tid] = pv;
  float ls = pv;
#pragma unroll
  for (int off = 32; off; off >>= 1) ls += __shfl_xor(ls, off);
  if ((tid & 63) == 0) red[4 + (tid >> 6)] = ls;
  __syncthreads();
  const float lc = (red[4] + red[5]) + (red[6] + red[7]);

  const int c4 = (tid & 31) << 2;
  const int sg = tid >> 5;
  float r0 = 0.f, r1 = 0.f, r2 = 0.f, r3 = 0.f;
  // rows beyond lenb have pv == 0 exactly -> skipping them is bit-identical
  const int nval = min(max(lenb - sbase - sg * 32, 0), 32);
  const float* vb = p.values + ((size_t)b * SSS + sbase + sg * 32) * NCC + c4;
#pragma unroll 4
  for (int i2 = 0; i2 < nval; ++i2) {
    const float pw = ps[sg * 32 + i2];
    float4 vv = ld4(vb + (size_t)i2 * NCC);
    r0 = fmaf(pw, vv.x, r0); r1 = fmaf(pw, vv.y, r1);
    r2 = fmaf(pw, vv.z, r2); r3 = fmaf(pw, vv.w, r3);
  }
  __syncthreads();
  *(float4*)&red[sg * 132 + c4] = make_float4(r0, r1, r2, r3);
  __syncthreads();
  float* pout = wsf + OFF_P + ((size_t)b * NCHK + ch) * 132;
  if (tid < NCC) {
    float sum = 0.f;
#pragma unroll
    for (int sg2 = 0; sg2 < 8; ++sg2) sum += red[sg2 * 132 + tid];
    stc(&pout[2 + tid], sum);
  }
  if (tid == 0) { stc(&pout[0], mc); stc(&pout[1], lc); }
  postflag(&sync[SY_BF(b)]);

  float gm = 0.f, gL = 1.f;
  if (ch == 0) {
    waitflag(&sync[SY_BF(b)], (unsigned)(NCHK * (a + 1)));
    const float* pb = wsf + OFF_P + (size_t)b * NCHK * 132;
    if (tid < 8)       red[tid] = ldc(&pb[tid * 132]);            // m_ch
    else if (tid < 16) red[tid] = ldc(&pb[(tid - 8) * 132 + 1]);  // L_ch
    __syncthreads();
    float m = red[0];
#pragma unroll
    for (int i = 1; i < 8; ++i) m = fmaxf(m, red[i]);
    float L = 0.f;
#pragma unroll
    for (int i = 0; i < 8; ++i) L += red[8 + i] * expf(red[i] - m);
    gm = m; gL = L;
    if (tid < NCC) {
      float v = 0.f;
#pragma unroll
      for (int c2 = 0; c2 < NCHK; ++c2)
        v += ldc(&pb[c2 * 132 + 2 + tid]) * expf(red[c2] - m);
      v /= L;
      stc(&wsf[OFF_CTX + b * NCC + tid], v);
      us[NHH + tid] = v;
    }
    if (tid == 0) { stc(&wsf[OFF_ML + b * 8], m); stc(&wsf[OFF_ML + b * 8 + 1], L); }
    postflag(&sync[SY_MF(b)]);
  } else if (wout) {
    waitflag(&sync[SY_MF(b)], (unsigned)(a + 1));
    gm = ldc(&wsf[OFF_ML + b * 8]);
    gL = ldc(&wsf[OFF_ML + b * 8 + 1]);
  }

  if (wout) {
    float* ao = p.out_att + ((size_t)t * BBB + b) * SSS;
    ao[s] = (msk ? expf(e - gm) : 0.f) / gL;
    if (ch == 0) {
      if (tid < NCC) {
        const float* wr = p.wc + (size_t)tid * (NHH + NCC);
        float s0 = 0.f, s1 = 0.f, s2 = 0.f, s3 = 0.f;
#pragma unroll 8
        for (int k = 0; k < NHH + NCC; k += 4) {
          float4 w = ld4(wr + k);
          s0 = fmaf(w.x, us[k],     s0); s1 = fmaf(w.y, us[k + 1], s1);
          s2 = fmaf(w.z, us[k + 2], s2); s3 = fmaf(w.w, us[k + 3], s3);
        }
        float z = (s0 + s1) + (s2 + s3) + p.bc[tid];
        zs[tid] = (z >= 0.f) ? z : 0.01f * z;
      }
      __syncthreads();
      if (tid < NINP) {
        const float* er = p.emb + tid * NCC;
        float s0 = 0.f, s1 = 0.f, s2 = 0.f, s3 = 0.f;
#pragma unroll 8
        for (int k = 0; k < NCC; k += 4) {
          float4 w = ld4(er + k);
          s0 = fmaf(w.x, zs[k],     s0); s1 = fmaf(w.y, zs[k + 1], s1);
          s2 = fmaf(w.z, zs[k + 2], s2); s3 = fmaf(w.w, zs[k + 3], s3);
        }
        const float lgt = (s0 + s1) + (s2 + s3) + p.bout[tid];
        p.out_logits[((size_t)t * BBB + b) * NINP + tid] = lgt;
        lg[tid] = lgt + gumbel((unsigned)(t * (BBB * NINP) + b * NINP + tid));
      }
      __syncthreads();
      if (tid == 0) {
        float bv = lg[0]; int bix = 0;
        for (int i = 1; i < NINP; ++i) if (lg[i] > bv) { bv = lg[i]; bix = i; }
        p.out_gen[t * BBB + b] = (float)bix;
      }
      __syncthreads();
    }
  }
}

extern "C" __global__ void __launch_bounds__(NTHR, 2)
decoder_kernel(Params p) {
  __shared__ float sh[11008];  // 44,032 B -> 2 blocks/CU
  const int bid = blockIdx.x;
  const int tid = threadIdx.x;
  // LSTM role (r8): unit-group ug (8 units), batch-octant boct (8 batches).
  // The 8 blocks sharing ug have bids congruent mod 8 -> same XCD under
  // round-robin dispatch -> their (4x larger) weight set is L2-resident.
  const int ug   = (bid & 7) * 8 + ((bid >> 3) & 7);
  const int boct = bid >> 6;
  unsigned epoch = 0;
  unsigned* sync = p.sync;
  float* wsf = p.wsf;

  // init: block (ug,boct) owns (b,j) pairs -> init its h (coherent) and c (plain)
  if (tid < 192) {
    const int l = tid >> 6, u = tid & 63;
    const int jl = u >> 3, bl = u & 7;
    const int b = boct * 8 + bl;
    const int j = ug * 8 + jl;
    stc(&wsf[OFF_H + ((size_t)l * BBB + b) * NHH + j], p.h0[l][j]);
    wsf[OFF_C + ((size_t)l * BBB + b) * NHH + j] = p.c0[l][j];
  }
  gbar(sync, epoch, bid);

  attend_phase(p, 0, -1, wsf + OFF_H + 2 * BBB * NHH, sh, bid, tid, false);
  gbar(sync, epoch, bid);

  for (int t = 0; t < TTT; ++t) {
    const float* hin = wsf + OFF_H + ((t & 1) ? 3 * BBB * NHH : 0);
    float* hout      = wsf + OFF_H + ((t & 1) ? 0 : 3 * BBB * NHH);

    lstm_layer<0>(p, t, hin, hout, sh, ug, boct, tid);
    gbar(sync, epoch, bid);
    lstm_layer<1>(p, t, hin, hout, sh, ug, boct, tid);
    gbar(sync, epoch, bid);
    lstm_layer<2>(p, t, hin, hout, sh, ug, boct, tid);
    gbar(sync, epoch, bid);
    attend_phase(p, t + 1, t, hout + 2 * BBB * NHH, sh, bid, tid, true);
    gbar(sync, epoch, bid);
  }
}

extern "C" void kernel_launch(void* const* d_in, const int* in_sizes, int n_in,
                              void* d_out, int out_size, void* d_ws, size_t ws_size,
                              hipStream_t stream) {
  Params p;
  p.keys   = (const float*)d_in[0];
  p.values = (const float*)d_in[1];
  p.lens   = (const int*)d_in[2];
  p.toks   = (const int*)d_in[3];
  p.emb    = (const float*)d_in[4];
  p.wq     = (const float*)d_in[5];
  p.bq     = (const float*)d_in[6];
  p.wc     = (const float*)d_in[7];
  p.bc     = (const float*)d_in[8];
  p.bout   = (const float*)d_in[9];
  for (int l = 0; l < 3; ++l) {
    p.wih[l] = (const float*)d_in[10 + 6 * l];
    p.whh[l] = (const float*)d_in[11 + 6 * l];
    p.bih[l] = (const float*)d_in[12 + 6 * l];
    p.bhh[l] = (const float*)d_in[13 + 6 * l];
    p.h0[l]  = (const float*)d_in[14 + 6 * l];
    p.c0[l]  = (const float*)d_in[15 + 6 * l];
  }
  float* out = (float*)d_out;
  p.out_logits = out;
  p.out_att    = out + (size_t)TTT * BBB * NINP;
  p.out_gen    = out + (size_t)TTT * BBB * NINP + (size_t)TTT * BBB * SSS;
  p.sync = (unsigned*)d_ws;
  p.wsf  = (float*)((char*)d_ws + 8192);

  hipMemsetAsync(d_ws, 0, 8192, stream);
  decoder_kernel<<<dim3(GDIM), dim3(NTHR), 0, stream>>>(p);
}